// Round 8
// baseline (721.728 us; speedup 1.0000x reference)
//
#include <hip/hip_runtime.h>
#include <math.h>

#define NN 25000
#define NE 400000
#define NINF -1e30f

typedef __attribute__((ext_vector_type(8))) short bf16x8;
typedef __attribute__((ext_vector_type(4))) float f32x4;

__device__ __forceinline__ float lrelu(float x){ return x > 0.f ? x : 0.01f*x; }
__device__ __forceinline__ float elu1(float x){ return x > 0.f ? x : (__expf(x)-1.f); }
__device__ __forceinline__ float sigm(float x){ return 1.f/(1.f+__expf(-x)); }
__device__ __forceinline__ float tanh_fast(float x){ float e=__expf(2.f*x); return 1.f - 2.f/(e+1.f); }
__device__ __forceinline__ short f2bf(float f){
    union { float f; unsigned u; } v; v.f = f;
    unsigned r = v.u + 0x7fff + ((v.u >> 16) & 1);   // RNE
    return (short)(r >> 16);
}
__device__ __forceinline__ float bf2f(short s){
    union { unsigned u; float f; } v; v.u = ((unsigned)(unsigned short)s) << 16;
    return v.f;
}
__device__ __forceinline__ unsigned cvtpk_bf16(float lo, float hi){
    unsigned r;
    asm volatile("v_cvt_pk_bf16_f32 %0, %1, %2" : "=v"(r) : "v"(lo), "v"(hi));
    return r;
}

// ---------------- pack weights into MFMA B-frag bf16 order ----------------
__global__ __launch_bounds__(256) void k_pack8(
    const float* __restrict__ w0, const float* __restrict__ w1,
    const float* __restrict__ w2, const float* __restrict__ w3,
    const float* __restrict__ w4, const float* __restrict__ w5,
    const float* __restrict__ w6, const float* __restrict__ w7,
    short* __restrict__ o0, short* __restrict__ o1, short* __restrict__ o2,
    short* __restrict__ o3, short* __restrict__ o4, short* __restrict__ o5,
    short* __restrict__ o6, short* __restrict__ o7)
{
    int b = blockIdx.x;
    if (b < 896){
        const float* w; short* o; int idx;
        if      (b < 192){ w=w0; o=o0; idx = b*256; }
        else if (b < 384){ w=w1; o=o1; idx = (b-192)*256; }
        else if (b < 576){ w=w2; o=o2; idx = (b-384)*256; }
        else if (b < 768){ w=w3; o=o3; idx = (b-576)*256; }
        else if (b < 832){ w=w4; o=o4; idx = (b-768)*256; }
        else             { w=w5; o=o5; idx = (b-832)*256; }
        idx += threadIdx.x;
        int i    = idx & 7;
        int lane = (idx >> 3) & 63;
        int ks   = (idx >> 9) & 3;
        int tile = idx >> 11;
        int row  = tile*16 + (lane & 15);
        int k    = ks*32 + ((lane >> 4) << 3) + i;
        o[idx] = f2bf(w[row*128 + k]);
    } else {
        const float* w; short* o; int idx; int pitch;
        if (b < 928){ w=w6; o=o6; idx = (b-896)*256; pitch = 39; }
        else        { w=w7; o=o7; idx = (b-928)*256; pitch = 49; }
        idx += threadIdx.x;
        int i    = idx & 7;
        int lane = (idx >> 3) & 63;
        int ks   = (idx >> 9) & 1;
        int tile = idx >> 10;
        int row  = tile*16 + (lane & 15);
        int k    = ks*32 + ((lane >> 4) << 3) + i;
        o[idx] = (k < 39) ? f2bf(w[row*pitch + k]) : (short)0;
    }
}

// ---------------- dual histogram (dst + src) ----------------
__global__ __launch_bounds__(256) void k_hist2(const int* __restrict__ src,
                                               const int* __restrict__ dst,
                                               unsigned* __restrict__ hd,
                                               unsigned* __restrict__ hs)
{
    int e = blockIdx.x*256 + threadIdx.x;
    if (e < NE){
        atomicAdd(&hd[dst[e]], 1u);
        atomicAdd(&hs[src[e]], 1u);
    }
}

// ---------------- dual exclusive scan ----------------
__global__ __launch_bounds__(1024) void k_scan2(
    const unsigned* __restrict__ hd, unsigned* __restrict__ cd,
    const unsigned* __restrict__ hs, unsigned* __restrict__ cs,
    int* __restrict__ srcptr)
{
    __shared__ unsigned ps[1024];
    const int issrc = blockIdx.x;
    const unsigned* h = issrc ? hs : hd;
    unsigned* c = issrc ? cs : cd;
    const int t = threadIdx.x;
    unsigned loc[25]; unsigned sum = 0;
    const int base = t*25;
    #pragma unroll
    for (int i=0;i<25;i++){ int n=base+i; unsigned v=(n<NN)?h[n]:0u; loc[i]=sum; sum+=v; }
    ps[t]=sum; __syncthreads();
    for (int off=1; off<1024; off<<=1){
        unsigned v = (t>=off)? ps[t-off] : 0u;
        __syncthreads();
        ps[t] += v;
        __syncthreads();
    }
    unsigned bex = (t==0)? 0u : ps[t-1];
    #pragma unroll
    for (int i=0;i<25;i++){
        int n=base+i;
        if (n<NN){
            unsigned off = bex + loc[i];
            c[n] = off;
            if (issrc) srcptr[n] = (int)off;
        }
    }
    if (issrc && t==1023) srcptr[NN] = NE;
}

// ---------------- dual scatter ----------------
__global__ __launch_bounds__(256) void k_scatter2(
    const int* __restrict__ src, const int* __restrict__ dst,
    unsigned* __restrict__ cd, unsigned* __restrict__ cs,
    int* __restrict__ se_dst, int* __restrict__ inv_dst,
    int* __restrict__ se2_id, int* __restrict__ se2_dst)
{
    int e = blockIdx.x*256 + threadIdx.x;
    if (e < NE){
        int d = dst[e], s = src[e];
        unsigned p = atomicAdd(&cd[d], 1u);
        se_dst[p] = d;
        inv_dst[e] = (int)p;
        unsigned q = atomicAdd(&cs[s], 1u);
        se2_id[q] = e;
        se2_dst[q] = d;
    }
}

// ---------------- fused layer-0 node prep: A16,B16,di,T16,GH16 (64 nodes/block) ----------------
__global__ __launch_bounds__(512) void k_l0_prep(
    const float* __restrict__ x,
    const float* __restrict__ ba, const float* __restrict__ bn,
    const float* __restrict__ aw,
    const short* __restrict__ wap, const short* __restrict__ wnp,
    const short* __restrict__ twp, const float* __restrict__ tb,
    const short* __restrict__ whhp, const float* __restrict__ bhh,
    short* __restrict__ A16, short* __restrict__ B16, float* __restrict__ di,
    short* __restrict__ T16, short* __restrict__ GH16)
{
    __shared__ short x_lds[64*72];
    __shared__ __align__(16) char A_lds[64*272];
    const int t = threadIdx.x;
    const int base = blockIdx.x << 6;
    for (int idx = t; idx < 64*64; idx += 512){
        int r = idx >> 6, k = idx & 63;
        int node = base + r;
        float v = (k < 39 && node < NN) ? x[(size_t)node*39 + k] : 0.f;
        x_lds[r*72 + k] = f2bf(v);
    }
    __syncthreads();
    const int w = t >> 6, lane = t & 63;
    const int l15 = lane & 15, lhi = lane >> 4;
    const int jb = w*16 + l15;
    f32x4 Aacc[4], Bacc[4];
    #pragma unroll
    for (int m=0; m<4; ++m){ Aacc[m] = (f32x4){0,0,0,0}; Bacc[m] = (f32x4){0,0,0,0}; }
    #pragma unroll
    for (int ks=0; ks<2; ++ks){
        bf16x8 af[4];
        #pragma unroll
        for (int m=0; m<4; ++m)
            af[m] = *(const bf16x8*)&x_lds[(m*16+l15)*72 + ks*32 + lhi*8];
        bf16x8 wfA = *(const bf16x8*)(wap + (size_t)((w*2 + ks)*64 + lane)*8);
        bf16x8 wfB = *(const bf16x8*)(wnp + (size_t)((w*2 + ks)*64 + lane)*8);
        #pragma unroll
        for (int m=0; m<4; ++m){
            Aacc[m] = __builtin_amdgcn_mfma_f32_16x16x32_bf16(af[m], wfA, Aacc[m], 0, 0, 0);
            Bacc[m] = __builtin_amdgcn_mfma_f32_16x16x32_bf16(af[m], wfB, Bacc[m], 0, 0, 0);
        }
    }
    {
        float bav = ba[jb], bnv = bn[jb];
        #pragma unroll
        for (int m=0; m<4; ++m){
            #pragma unroll
            for (int reg=0; reg<4; ++reg){
                int e = m*16 + lhi*4 + reg;
                int node = base + e;
                float avv = lrelu(Aacc[m][reg] + bav);
                short ab16 = f2bf(avv);
                *(short*)(A_lds + e*272 + jb*2) = ab16;
                if (node < NN){
                    A16[(size_t)node*128 + jb] = ab16;
                    B16[(size_t)node*128 + jb] = f2bf(Bacc[m][reg] + bnv);
                }
            }
        }
    }
    __syncthreads();
    {
        float a0 = aw[lane], a1 = aw[64+lane];
        for (int i=0;i<8;++i){
            int r = w*8 + i;
            int node = base + r;
            float v0 = bf2f(*(const short*)(A_lds + r*272 + lane*2));
            float v1 = bf2f(*(const short*)(A_lds + r*272 + 128 + lane*2));
            float pa = v0*a0 + v1*a1;
            #pragma unroll
            for (int off=32; off; off>>=1) pa += __shfl_xor(pa, off);
            if (lane==0 && node<NN) di[node] = pa;
        }
    }
    f32x4 Tacc[4], gh[4][3];
    {
        float tbv = tb[jb];
        #pragma unroll
        for (int m=0; m<4; ++m) Tacc[m] = (f32x4){tbv, tbv, tbv, tbv};
        #pragma unroll
        for (int g=0; g<3; ++g){
            float bv = bhh[g*128 + jb];
            #pragma unroll
            for (int m=0; m<4; ++m) gh[m][g] = (f32x4){bv, bv, bv, bv};
        }
    }
    #pragma unroll
    for (int ks=0; ks<4; ++ks){
        bf16x8 af[4];
        #pragma unroll
        for (int m=0; m<4; ++m)
            af[m] = *(const bf16x8*)(A_lds + (m*16+l15)*272 + ks*64 + (lhi<<4));
        bf16x8 tf = *(const bf16x8*)(twp + (size_t)((w*4 + ks)*64 + lane)*8);
        #pragma unroll
        for (int m=0; m<4; ++m)
            Tacc[m] = __builtin_amdgcn_mfma_f32_16x16x32_bf16(af[m], tf, Tacc[m], 0, 0, 0);
        #pragma unroll
        for (int g=0; g<3; ++g){
            bf16x8 wf = *(const bf16x8*)(whhp + (size_t)(((g*8+w)*4 + ks)*64 + lane)*8);
            #pragma unroll
            for (int m=0; m<4; ++m)
                gh[m][g] = __builtin_amdgcn_mfma_f32_16x16x32_bf16(af[m], wf, gh[m][g], 0, 0, 0);
        }
    }
    #pragma unroll
    for (int m=0; m<4; ++m){
        #pragma unroll
        for (int reg=0; reg<4; ++reg){
            int node = base + m*16 + lhi*4 + reg;
            if (node < NN){
                T16[(size_t)node*128 + jb]        = f2bf(Tacc[m][reg]);
                GH16[(size_t)node*384 + jb]       = f2bf(gh[m][0][reg]);
                GH16[(size_t)node*384 + 128 + jb] = f2bf(gh[m][1][reg]);
                GH16[(size_t)node*384 + 256 + jb] = f2bf(gh[m][2][reg]);
            }
        }
    }
}

// ---------------- layer 1 prep: out0 -> x16 (+LDS), di, dj, T16, GH16 ----------------
__global__ __launch_bounds__(512) void k_l1_prep(
    const float* __restrict__ out0, const float* __restrict__ aw,
    const short* __restrict__ twp, const float* __restrict__ tb,
    const short* __restrict__ whhp, const float* __restrict__ bhh,
    short* __restrict__ x16, float* __restrict__ di, float* __restrict__ dj,
    short* __restrict__ T16, short* __restrict__ GH16)
{
    __shared__ __align__(16) char x_lds[64*272];
    const int t = threadIdx.x;
    const int base = blockIdx.x << 6;
    {
        int r = t >> 3, c0 = (t & 7) * 16;
        int node = base + r;
        int nc = node < NN ? node : NN-1;
        const float4* sp = (const float4*)(out0 + (size_t)nc*128 + c0);
        float4 f0 = sp[0], f1 = sp[1], f2 = sp[2], f3 = sp[3];
        union { short s[16]; int4 v[2]; } u;
        u.s[0]=f2bf(f0.x); u.s[1]=f2bf(f0.y); u.s[2]=f2bf(f0.z); u.s[3]=f2bf(f0.w);
        u.s[4]=f2bf(f1.x); u.s[5]=f2bf(f1.y); u.s[6]=f2bf(f1.z); u.s[7]=f2bf(f1.w);
        u.s[8]=f2bf(f2.x); u.s[9]=f2bf(f2.y); u.s[10]=f2bf(f2.z); u.s[11]=f2bf(f2.w);
        u.s[12]=f2bf(f3.x); u.s[13]=f2bf(f3.y); u.s[14]=f2bf(f3.z); u.s[15]=f2bf(f3.w);
        *(int4*)(x_lds + r*272 + c0*2)      = u.v[0];
        *(int4*)(x_lds + r*272 + c0*2 + 16) = u.v[1];
        if (node < NN){
            *(int4*)(x16 + (size_t)node*128 + c0)     = u.v[0];
            *(int4*)(x16 + (size_t)node*128 + c0 + 8) = u.v[1];
        }
    }
    __syncthreads();
    const int w = t >> 6, lane = t & 63;
    {
        float a0 = aw[lane], a1 = aw[64+lane], a2 = aw[128+lane], a3 = aw[192+lane];
        for (int i=0;i<8;++i){
            int r = w*8 + i;
            int node = base + r;
            float v0 = bf2f(*(const short*)(x_lds + r*272 + lane*2));
            float v1 = bf2f(*(const short*)(x_lds + r*272 + 128 + lane*2));
            float pa = v0*a0 + v1*a1;
            float pb = v0*a2 + v1*a3;
            #pragma unroll
            for (int off=32; off; off>>=1){ pa += __shfl_xor(pa,off); pb += __shfl_xor(pb,off); }
            if (lane==0 && node<NN){ di[node]=pa; dj[node]=pb; }
        }
    }
    const int l15 = lane & 15, lhi = lane >> 4;
    const int jb = w*16 + l15;
    f32x4 Tacc[4], gh[4][3];
    {
        float tbv = tb[jb];
        #pragma unroll
        for (int m=0; m<4; ++m) Tacc[m] = (f32x4){tbv, tbv, tbv, tbv};
        #pragma unroll
        for (int g=0; g<3; ++g){
            float bv = bhh[g*128 + jb];
            #pragma unroll
            for (int m=0; m<4; ++m) gh[m][g] = (f32x4){bv, bv, bv, bv};
        }
    }
    #pragma unroll
    for (int ks=0; ks<4; ++ks){
        bf16x8 af[4];
        #pragma unroll
        for (int m=0; m<4; ++m)
            af[m] = *(const bf16x8*)(x_lds + (m*16+l15)*272 + ks*64 + (lhi<<4));
        bf16x8 tf = *(const bf16x8*)(twp + (size_t)((w*4 + ks)*64 + lane)*8);
        #pragma unroll
        for (int m=0; m<4; ++m)
            Tacc[m] = __builtin_amdgcn_mfma_f32_16x16x32_bf16(af[m], tf, Tacc[m], 0, 0, 0);
        #pragma unroll
        for (int g=0; g<3; ++g){
            bf16x8 wf = *(const bf16x8*)(whhp + (size_t)(((g*8+w)*4 + ks)*64 + lane)*8);
            #pragma unroll
            for (int m=0; m<4; ++m)
                gh[m][g] = __builtin_amdgcn_mfma_f32_16x16x32_bf16(af[m], wf, gh[m][g], 0, 0, 0);
        }
    }
    #pragma unroll
    for (int m=0; m<4; ++m){
        #pragma unroll
        for (int reg=0; reg<4; ++reg){
            int node = base + m*16 + lhi*4 + reg;
            if (node < NN){
                T16[(size_t)node*128 + jb]        = f2bf(Tacc[m][reg]);
                GH16[(size_t)node*384 + jb]       = f2bf(gh[m][0][reg]);
                GH16[(size_t)node*384 + 128 + jb] = f2bf(gh[m][1][reg]);
                GH16[(size_t)node*384 + 256 + jb] = f2bf(gh[m][2][reg]);
            }
        }
    }
}

// ---------------- fused align+softmax, layer 0 ----------------
__global__ __launch_bounds__(256) void k_align0(
    const int* __restrict__ srcptr, const int* __restrict__ se2_id,
    const int* __restrict__ se2_dst, const int* __restrict__ inv_dst,
    const float* __restrict__ ea, const short* __restrict__ B16,
    const float* __restrict__ wn, const float* __restrict__ aw,
    const float* __restrict__ ab, const float* __restrict__ di,
    float* __restrict__ evu_tmp, float* __restrict__ avu)
{
    const int lane = threadIdx.x & 63;
    const int node = blockIdx.x*4 + (threadIdx.x >> 6);
    if (node >= NN) return;
    const int start = srcptr[node], end = srcptr[node+1];
    if (start >= end) return;
    float wn2a[10], wn2b[10];
    #pragma unroll
    for (int k=0;k<10;++k){
        wn2a[k] = wn[lane*49 + 39 + k];
        wn2b[k] = wn[(lane+64)*49 + 39 + k];
    }
    const float awa = aw[128+lane], awb = aw[192+lane];
    const float abv = ab[0];
    const float v1b = bf2f(B16[(size_t)node*128 + lane]);
    const float v2b = bf2f(B16[(size_t)node*128 + 64 + lane]);
    const int deg = end - start;
    if (deg <= 64){
        int myeid = 0; float mydi = 0.f; float ear[10];
        if (lane < deg){
            int pos = start + lane;
            myeid = se2_id[pos];
            mydi  = di[se2_dst[pos]];
            #pragma unroll
            for (int k=0;k<10;++k) ear[k] = ea[(size_t)myeid*10 + k];
        }
        float pv = NINF;
        for (int i=0;i<deg;++i){
            float v1 = v1b, v2 = v2b;
            #pragma unroll
            for (int k=0;k<10;++k){
                float e = __shfl(ear[k], i);
                v1 += e*wn2a[k]; v2 += e*wn2b[k];
            }
            v1 = lrelu(v1); v2 = lrelu(v2);
            float p = v1*awa + v2*awb;
            #pragma unroll
            for (int off=32; off; off>>=1) p += __shfl_xor(p, off);
            float pe = lrelu(p + __shfl(mydi, i) + abv);
            if (lane == i) pv = pe;
        }
        float cm = pv;
        #pragma unroll
        for (int off=32; off; off>>=1) cm = fmaxf(cm, __shfl_xor(cm, off));
        float ex = (lane < deg) ? __expf(pv - cm) : 0.f;
        float cs = ex;
        #pragma unroll
        for (int off=32; off; off>>=1) cs += __shfl_xor(cs, off);
        if (lane < deg) avu[inv_dst[myeid]] = ex / (cs + 1e-16f);
    } else {
        float mrun = NINF, srun = 0.f;
        for (int c0 = start; c0 < end; c0 += 64){
            int nE = min(64, end - c0);
            int myeid=0; float mydi=0.f; float ear[10];
            if (lane < nE){
                int pos = c0 + lane;
                myeid = se2_id[pos];
                mydi = di[se2_dst[pos]];
                #pragma unroll
                for (int k=0;k<10;++k) ear[k] = ea[(size_t)myeid*10 + k];
            }
            float pv = NINF;
            for (int i=0;i<nE;++i){
                float v1=v1b, v2=v2b;
                #pragma unroll
                for (int k=0;k<10;++k){
                    float e = __shfl(ear[k], i);
                    v1 += e*wn2a[k]; v2 += e*wn2b[k];
                }
                v1=lrelu(v1); v2=lrelu(v2);
                float p = v1*awa + v2*awb;
                #pragma unroll
                for (int off=32; off; off>>=1) p += __shfl_xor(p, off);
                float pe = lrelu(p + __shfl(mydi,i) + abv);
                if (lane == i) pv = pe;
            }
            if (lane < nE) evu_tmp[c0+lane] = pv;
            float cm = pv;
            #pragma unroll
            for (int off=32; off; off>>=1) cm = fmaxf(cm, __shfl_xor(cm,off));
            float nm = fmaxf(mrun, cm);
            float exs = (lane<nE)? __expf(pv-nm) : 0.f;
            float cs = exs;
            #pragma unroll
            for (int off=32; off; off>>=1) cs += __shfl_xor(cs, off);
            srun = srun*__expf(mrun-nm) + cs;
            mrun = nm;
        }
        float inv = 1.f/(srun + 1e-16f);
        for (int c0 = start; c0 < end; c0 += 64){
            int nE = min(64, end - c0);
            if (lane < nE){
                int pos = c0+lane;
                float pv = evu_tmp[pos];
                avu[inv_dst[se2_id[pos]]] = __expf(pv - mrun)*inv;
            }
        }
    }
}

// ---------------- fused align+softmax, layer 1 ----------------
__global__ __launch_bounds__(256) void k_align1(
    const int* __restrict__ srcptr, const int* __restrict__ se2_id,
    const int* __restrict__ se2_dst, const int* __restrict__ inv_dst,
    const float* __restrict__ di, const float* __restrict__ dj,
    const float* __restrict__ ab,
    float* __restrict__ evu_tmp, float* __restrict__ avu)
{
    const int lane = threadIdx.x & 63;
    const int node = blockIdx.x*4 + (threadIdx.x >> 6);
    if (node >= NN) return;
    const int start = srcptr[node], end = srcptr[node+1];
    if (start >= end) return;
    const float djs = dj[node] + ab[0];
    const int deg = end - start;
    if (deg <= 64){
        int myeid = 0; float pv = NINF;
        if (lane < deg){
            int pos = start + lane;
            myeid = se2_id[pos];
            pv = lrelu(di[se2_dst[pos]] + djs);
        }
        float cm = pv;
        #pragma unroll
        for (int off=32; off; off>>=1) cm = fmaxf(cm, __shfl_xor(cm, off));
        float ex = (lane < deg) ? __expf(pv - cm) : 0.f;
        float cs = ex;
        #pragma unroll
        for (int off=32; off; off>>=1) cs += __shfl_xor(cs, off);
        if (lane < deg) avu[inv_dst[myeid]] = ex / (cs + 1e-16f);
    } else {
        float mrun = NINF, srun = 0.f;
        for (int c0 = start; c0 < end; c0 += 64){
            int nE = min(64, end - c0);
            float pv = NINF;
            if (lane < nE){
                int pos = c0 + lane;
                pv = lrelu(di[se2_dst[pos]] + djs);
                evu_tmp[pos] = pv;
            }
            float cm = pv;
            #pragma unroll
            for (int off=32; off; off>>=1) cm = fmaxf(cm, __shfl_xor(cm,off));
            float nm = fmaxf(mrun, cm);
            float exs = (lane<nE)? __expf(pv-nm) : 0.f;
            float cs = exs;
            #pragma unroll
            for (int off=32; off; off>>=1) cs += __shfl_xor(cs, off);
            srun = srun*__expf(mrun-nm) + cs;
            mrun = nm;
        }
        float inv = 1.f/(srun + 1e-16f);
        for (int c0 = start; c0 < end; c0 += 64){
            int nE = min(64, end - c0);
            if (lane < nE){
                int pos = c0+lane;
                avu[inv_dst[se2_id[pos]]] = __expf(evu_tmp[pos] - mrun)*inv;
            }
        }
    }
}

// ---------------- heavy per-edge on dst-sorted edges ----------------
// 64 edges/block, 512 threads, 17.8 KB LDS. Independent gh/hp gathers (ILP);
// GRU fused into run-compressed direct atomicAdd from C-frag registers.
__global__ __launch_bounds__(512) void k_edge_gru(
    const int* __restrict__ se_dst,
    const float* __restrict__ avu,
    const short* __restrict__ T16, const short* __restrict__ GH16,
    const short* __restrict__ HP16,
    const short* __restrict__ wihp, const float* __restrict__ bih,
    float* __restrict__ out)
{
    __shared__ __align__(16) char c_lds[64*272];    // c bf16
    __shared__ __align__(16) int dsts[64];
    __shared__ float av[64];
    const int t = threadIdx.x;
    const int p0 = blockIdx.x << 6;
    if (t < 64){
        dsts[t] = se_dst[p0 + t];
        av[t] = avu[p0 + t];
    }
    __syncthreads();
    // ---- c = elu(av * T16[dst]) -> c_lds bf16 ----
    #pragma unroll
    for (int it=0; it<2; ++it){
        int cid = it*512 + t;
        int row = cid >> 4, ch = cid & 15;
        int d = dsts[row];
        float a = av[row];
        bf16x8 tv = *(const bf16x8*)(T16 + (size_t)d*128 + ch*8);
        float c0 = elu1(a*bf2f(tv[0])), c1 = elu1(a*bf2f(tv[1]));
        float c2 = elu1(a*bf2f(tv[2])), c3 = elu1(a*bf2f(tv[3]));
        float c4 = elu1(a*bf2f(tv[4])), c5 = elu1(a*bf2f(tv[5]));
        float c6 = elu1(a*bf2f(tv[6])), c7 = elu1(a*bf2f(tv[7]));
        int4 pk;
        pk.x = (int)cvtpk_bf16(c0, c1);
        pk.y = (int)cvtpk_bf16(c2, c3);
        pk.z = (int)cvtpk_bf16(c4, c5);
        pk.w = (int)cvtpk_bf16(c6, c7);
        *(int4*)(c_lds + row*272 + ch*16) = pk;
    }
    __syncthreads();
    const int w = t >> 6, lane = t & 63;
    const int l15 = lane & 15, lhi = lane >> 4;
    const int jb = w*16 + l15;
    // ---- gi GEMM ----
    f32x4 gi[4][3];
    #pragma unroll
    for (int g=0; g<3; ++g){
        float bv = bih[g*128 + jb];
        #pragma unroll
        for (int m=0; m<4; ++m) gi[m][g] = (f32x4){bv, bv, bv, bv};
    }
    #pragma unroll
    for (int ks=0; ks<4; ++ks){
        bf16x8 cf[4];
        #pragma unroll
        for (int m=0; m<4; ++m)
            cf[m] = *(const bf16x8*)(c_lds + (m*16+l15)*272 + ks*64 + (lhi<<4));
        #pragma unroll
        for (int g=0; g<3; ++g){
            bf16x8 wf = *(const bf16x8*)(wihp + (size_t)(((g*8+w)*4 + ks)*64 + lane)*8);
            #pragma unroll
            for (int m=0; m<4; ++m)
                gi[m][g] = __builtin_amdgcn_mfma_f32_16x16x32_bf16(cf[m], wf, gi[m][g], 0, 0, 0);
        }
    }
    // ---- GRU epilogue + run-compressed direct atomic scatter (no LDS staging) ----
    #pragma unroll
    for (int m=0; m<4; ++m){
        int4 dv = *(const int4*)&dsts[m*16 + lhi*4];
        int dd[4] = {dv.x, dv.y, dv.z, dv.w};
        // independent gathers for all 4 regs (ILP over ~L1/L2-hot lines)
        float ghr[4], ghz[4], ghn[4], hp[4];
        #pragma unroll
        for (int reg=0; reg<4; ++reg){
            const short* gh = GH16 + (size_t)dd[reg]*384 + jb;
            ghr[reg] = bf2f(gh[0]);
            ghz[reg] = bf2f(gh[128]);
            ghn[reg] = bf2f(gh[256]);
            hp[reg]  = bf2f(HP16[(size_t)dd[reg]*128 + jb]);
        }
        float acc = 0.f; int prev = -1;
        #pragma unroll
        for (int reg=0; reg<4; ++reg){
            float r = sigm(gi[m][0][reg] + ghr[reg]);
            float z = sigm(gi[m][1][reg] + ghz[reg]);
            float n = tanh_fast(gi[m][2][reg] + r*ghn[reg]);
            float h = (1.f - z)*n + z*hp[reg];
            if (dd[reg] == prev) acc += h;
            else {
                if (prev >= 0) atomicAdd(out + (size_t)prev*128 + jb, acc);
                acc = h; prev = dd[reg];
            }
        }
        atomicAdd(out + (size_t)prev*128 + jb, acc);
    }
}

extern "C" void kernel_launch(void* const* d_in, const int* in_sizes, int n_in,
                              void* d_out, int out_size, void* d_ws, size_t ws_size,
                              hipStream_t stream) {
    const float* x    = (const float*)d_in[0];
    const int*   eidx = (const int*)d_in[1];
    const int*   esrc = eidx;
    const int*   edst = eidx + NE;
    const float* ea   = (const float*)d_in[2];
    const float* a_w  = (const float*)d_in[3];
    const float* a_b  = (const float*)d_in[4];
    const float* n_w  = (const float*)d_in[5];
    const float* n_b  = (const float*)d_in[6];
    const float* al_w0= (const float*)d_in[7];
    const float* al_b0= (const float*)d_in[8];
    const float* t_w0 = (const float*)d_in[9];
    const float* t_b0 = (const float*)d_in[10];
    const float* wih0 = (const float*)d_in[11];
    const float* whh0 = (const float*)d_in[12];
    const float* bih0 = (const float*)d_in[13];
    const float* bhh0 = (const float*)d_in[14];
    const float* al_w1= (const float*)d_in[15];
    const float* al_b1= (const float*)d_in[16];
    const float* t_w1 = (const float*)d_in[17];
    const float* t_b1 = (const float*)d_in[18];
    const float* wih1 = (const float*)d_in[19];
    const float* whh1 = (const float*)d_in[20];
    const float* bih1 = (const float*)d_in[21];
    const float* bhh1 = (const float*)d_in[22];

    float* ws   = (float*)d_ws;
    float* out0 = ws;                               // NN*128 f
    float* avu  = out0 + (size_t)NN*128;            // NE
    float* evu_tmp = avu + NE;                      // NE
    float* di   = evu_tmp + NE;                     // NN
    float* dj   = di + NN;                          // NN
    unsigned* hist_d = (unsigned*)(dj + NN);        // NN
    unsigned* hist_s = hist_d + NN;                 // NN
    unsigned* cur_d  = hist_s + NN;                 // NN
    unsigned* cur_s  = cur_d + NN;                  // NN
    int* srcptr = (int*)(cur_s + NN);               // NN+1
    int* se_dst  = srcptr + NN + 1;                 // NE
    int* inv_dst = se_dst + NE;                     // NE
    int* se2_id  = inv_dst + NE;                    // NE
    int* se2_dst = se2_id + NE;                     // NE
    short* A16  = (short*)(se2_dst + NE);           // NN*128
    short* BX16 = A16 + (size_t)NN*128;             // B16 (l0) then x16 (l1)
    short* T16  = BX16 + (size_t)NN*128;            // NN*128
    short* GH16 = T16 + (size_t)NN*128;             // NN*384
    short* wp0  = GH16 + (size_t)NN*384;            // 49152 each
    short* wp1  = wp0 + 49152;
    short* wh0p = wp1 + 49152;
    short* wh1p = wh0p + 49152;
    short* tp0  = wh1p + 49152;                     // 16384 each
    short* tp1  = tp0 + 16384;
    short* wap  = tp1 + 16384;                      // 8192 each (K64 packs)
    short* wnp  = wap + 8192;

    hipMemsetAsync(out0, 0, (size_t)NN*128*sizeof(float), stream);
    hipMemsetAsync(d_out, 0, (size_t)NN*128*sizeof(float), stream);
    hipMemsetAsync(hist_d, 0, (size_t)2*NN*sizeof(unsigned), stream);

    dim3 blk(256);
    k_pack8<<<dim3(960), blk, 0, stream>>>(wih0, wih1, whh0, whh1, t_w0, t_w1, a_w, n_w,
                                           wp0, wp1, wh0p, wh1p, tp0, tp1, wap, wnp);
    k_hist2<<<dim3((NE+255)/256), blk, 0, stream>>>(esrc, edst, hist_d, hist_s);
    k_scan2<<<dim3(2), dim3(1024), 0, stream>>>(hist_d, cur_d, hist_s, cur_s, srcptr);
    k_scatter2<<<dim3((NE+255)/256), blk, 0, stream>>>(esrc, edst, cur_d, cur_s,
                                                       se_dst, inv_dst, se2_id, se2_dst);
    // ---- layer 0 ----
    k_l0_prep<<<dim3((NN+63)/64), dim3(512), 0, stream>>>(x, a_b, n_b, al_w0, wap, wnp,
                                                          tp0, t_b0, wh0p, bhh0,
                                                          A16, BX16, di, T16, GH16);
    k_align0<<<dim3((NN+3)/4), blk, 0, stream>>>(srcptr, se2_id, se2_dst, inv_dst,
                                                 ea, BX16, n_w, al_w0, al_b0, di, evu_tmp, avu);
    k_edge_gru<<<dim3(NE/64), dim3(512), 0, stream>>>(se_dst, avu, T16, GH16, A16,
                                                      wp0, bih0, out0);
    // ---- layer 1 ----
    k_l1_prep<<<dim3((NN+63)/64), dim3(512), 0, stream>>>(out0, al_w1, tp1, t_b1, wh1p, bhh1,
                                                          BX16, di, dj, T16, GH16);
    k_align1<<<dim3((NN+3)/4), blk, 0, stream>>>(srcptr, se2_id, se2_dst, inv_dst,
                                                 di, dj, al_b1, evu_tmp, avu);
    k_edge_gru<<<dim3(NE/64), dim3(512), 0, stream>>>(se_dst, avu, T16, GH16, BX16,
                                                      wp1, bih1, (float*)d_out);
}

// Round 9
// 604.225 us; speedup vs baseline: 1.1945x; 1.1945x over previous
//
#include <hip/hip_runtime.h>
#include <math.h>

#define NN 25000
#define NE 400000
#define NINF -1e30f

typedef __attribute__((ext_vector_type(8))) short bf16x8;
typedef __attribute__((ext_vector_type(4))) float f32x4;

__device__ __forceinline__ float lrelu(float x){ return x > 0.f ? x : 0.01f*x; }
__device__ __forceinline__ float elu1(float x){ return x > 0.f ? x : (__expf(x)-1.f); }
__device__ __forceinline__ float sigm(float x){ return 1.f/(1.f+__expf(-x)); }
__device__ __forceinline__ float tanh_fast(float x){ float e=__expf(2.f*x); return 1.f - 2.f/(e+1.f); }
__device__ __forceinline__ short f2bf(float f){
    union { float f; unsigned u; } v; v.f = f;
    unsigned r = v.u + 0x7fff + ((v.u >> 16) & 1);   // RNE
    return (short)(r >> 16);
}
__device__ __forceinline__ float bf2f(short s){
    union { unsigned u; float f; } v; v.u = ((unsigned)(unsigned short)s) << 16;
    return v.f;
}
__device__ __forceinline__ unsigned cvtpk_bf16(float lo, float hi){
    unsigned r;
    asm("v_cvt_pk_bf16_f32 %0, %1, %2" : "=v"(r) : "v"(lo), "v"(hi));
    return r;
}

// ================= setup: weight packing (blocks 0..959) + histogram (960..2522) ==========
__global__ __launch_bounds__(256) void k_setup(
    const float* __restrict__ w0, const float* __restrict__ w1,
    const float* __restrict__ w2, const float* __restrict__ w3,
    const float* __restrict__ w4, const float* __restrict__ w5,
    const float* __restrict__ w6, const float* __restrict__ w7,
    short* __restrict__ o0, short* __restrict__ o1, short* __restrict__ o2,
    short* __restrict__ o3, short* __restrict__ o4, short* __restrict__ o5,
    short* __restrict__ o6, short* __restrict__ o7,
    const int* __restrict__ src, const int* __restrict__ dst,
    unsigned* __restrict__ hd, unsigned* __restrict__ hs)
{
    int b = blockIdx.x;
    if (b < 896){
        const float* w; short* o; int idx;
        if      (b < 192){ w=w0; o=o0; idx = b*256; }
        else if (b < 384){ w=w1; o=o1; idx = (b-192)*256; }
        else if (b < 576){ w=w2; o=o2; idx = (b-384)*256; }
        else if (b < 768){ w=w3; o=o3; idx = (b-576)*256; }
        else if (b < 832){ w=w4; o=o4; idx = (b-768)*256; }
        else             { w=w5; o=o5; idx = (b-832)*256; }
        idx += threadIdx.x;
        int i    = idx & 7;
        int lane = (idx >> 3) & 63;
        int ks   = (idx >> 9) & 3;
        int tile = idx >> 11;
        int row  = tile*16 + (lane & 15);
        int k    = ks*32 + ((lane >> 4) << 3) + i;
        o[idx] = f2bf(w[row*128 + k]);
    } else if (b < 960){
        const float* w; short* o; int idx; int pitch;
        if (b < 928){ w=w6; o=o6; idx = (b-896)*256; pitch = 39; }
        else        { w=w7; o=o7; idx = (b-928)*256; pitch = 49; }
        idx += threadIdx.x;
        int i    = idx & 7;
        int lane = (idx >> 3) & 63;
        int ks   = (idx >> 9) & 1;
        int tile = idx >> 10;
        int row  = tile*16 + (lane & 15);
        int k    = ks*32 + ((lane >> 4) << 3) + i;
        o[idx] = (k < 39) ? f2bf(w[row*pitch + k]) : (short)0;
    } else {
        int e = (b-960)*256 + threadIdx.x;
        if (e < NE){
            atomicAdd(&hd[dst[e]], 1u);
            atomicAdd(&hs[src[e]], 1u);
        }
    }
}

// ================= dual exclusive scan =================
__global__ __launch_bounds__(1024) void k_scan2(
    const unsigned* __restrict__ hd, unsigned* __restrict__ cd,
    const unsigned* __restrict__ hs, unsigned* __restrict__ cs,
    int* __restrict__ srcptr)
{
    __shared__ unsigned ps[1024];
    const int issrc = blockIdx.x;
    const unsigned* h = issrc ? hs : hd;
    unsigned* c = issrc ? cs : cd;
    const int t = threadIdx.x;
    unsigned loc[25]; unsigned sum = 0;
    const int base = t*25;
    #pragma unroll
    for (int i=0;i<25;i++){ int n=base+i; unsigned v=(n<NN)?h[n]:0u; loc[i]=sum; sum+=v; }
    ps[t]=sum; __syncthreads();
    for (int off=1; off<1024; off<<=1){
        unsigned v = (t>=off)? ps[t-off] : 0u;
        __syncthreads();
        ps[t] += v;
        __syncthreads();
    }
    unsigned bex = (t==0)? 0u : ps[t-1];
    #pragma unroll
    for (int i=0;i<25;i++){
        int n=base+i;
        if (n<NN){
            unsigned off = bex + loc[i];
            c[n] = off;
            if (issrc) srcptr[n] = (int)off;
        }
    }
    if (issrc && t==1023) srcptr[NN] = NE;
}

// ================= big: l0_prep (blocks 0..390) + scatter&zero (391..1172) =================
__global__ __launch_bounds__(512) void k_big(
    // l0_prep args
    const float* __restrict__ x,
    const float* __restrict__ ba, const float* __restrict__ bn,
    const float* __restrict__ aw,
    const short* __restrict__ wap, const short* __restrict__ wnp,
    const short* __restrict__ twp, const float* __restrict__ tb,
    const short* __restrict__ whhp, const float* __restrict__ bhh,
    short* __restrict__ A16, short* __restrict__ B16, float* __restrict__ di,
    short* __restrict__ T16, short* __restrict__ GH16,
    // scatter args
    const int* __restrict__ src, const int* __restrict__ dst,
    unsigned* __restrict__ cd, unsigned* __restrict__ cs,
    int* __restrict__ se_dst, int* __restrict__ inv_dst,
    int* __restrict__ se2_id, int* __restrict__ se2_dst,
    float* __restrict__ out0z, float* __restrict__ doutz)
{
    __shared__ short x_lds[64*72];
    __shared__ __align__(16) char A_lds[64*272];
    const int t = threadIdx.x;
    const int b = blockIdx.x;
    if (b >= 391){
        int e = (b-391)*512 + t;
        if (e < NE){
            float4 z = {0.f,0.f,0.f,0.f};
            *(float4*)(out0z + (size_t)e*8)     = z;
            *(float4*)(out0z + (size_t)e*8 + 4) = z;
            *(float4*)(doutz + (size_t)e*8)     = z;
            *(float4*)(doutz + (size_t)e*8 + 4) = z;
            int d = dst[e], s = src[e];
            unsigned p = atomicAdd(&cd[d], 1u);
            se_dst[p] = d;
            inv_dst[e] = (int)p;
            unsigned q = atomicAdd(&cs[s], 1u);
            se2_id[q] = e;
            se2_dst[q] = d;
        }
        return;
    }
    const int base = b << 6;
    for (int idx = t; idx < 64*64; idx += 512){
        int r = idx >> 6, k = idx & 63;
        int node = base + r;
        float v = (k < 39 && node < NN) ? x[(size_t)node*39 + k] : 0.f;
        x_lds[r*72 + k] = f2bf(v);
    }
    __syncthreads();
    const int w = t >> 6, lane = t & 63;
    const int l15 = lane & 15, lhi = lane >> 4;
    const int jb = w*16 + l15;
    f32x4 Aacc[4], Bacc[4];
    #pragma unroll
    for (int m=0; m<4; ++m){ Aacc[m] = (f32x4){0,0,0,0}; Bacc[m] = (f32x4){0,0,0,0}; }
    #pragma unroll
    for (int ks=0; ks<2; ++ks){
        bf16x8 af[4];
        #pragma unroll
        for (int m=0; m<4; ++m)
            af[m] = *(const bf16x8*)&x_lds[(m*16+l15)*72 + ks*32 + lhi*8];
        bf16x8 wfA = *(const bf16x8*)(wap + (size_t)((w*2 + ks)*64 + lane)*8);
        bf16x8 wfB = *(const bf16x8*)(wnp + (size_t)((w*2 + ks)*64 + lane)*8);
        #pragma unroll
        for (int m=0; m<4; ++m){
            Aacc[m] = __builtin_amdgcn_mfma_f32_16x16x32_bf16(af[m], wfA, Aacc[m], 0, 0, 0);
            Bacc[m] = __builtin_amdgcn_mfma_f32_16x16x32_bf16(af[m], wfB, Bacc[m], 0, 0, 0);
        }
    }
    {
        float bav = ba[jb], bnv = bn[jb];
        #pragma unroll
        for (int m=0; m<4; ++m){
            #pragma unroll
            for (int reg=0; reg<4; ++reg){
                int e = m*16 + lhi*4 + reg;
                int node = base + e;
                float avv = lrelu(Aacc[m][reg] + bav);
                short ab16 = f2bf(avv);
                *(short*)(A_lds + e*272 + jb*2) = ab16;
                if (node < NN){
                    A16[(size_t)node*128 + jb] = ab16;
                    B16[(size_t)node*128 + jb] = f2bf(Bacc[m][reg] + bnv);
                }
            }
        }
    }
    __syncthreads();
    {
        float a0 = aw[lane], a1 = aw[64+lane];
        for (int i=0;i<8;++i){
            int r = w*8 + i;
            int node = base + r;
            float v0 = bf2f(*(const short*)(A_lds + r*272 + lane*2));
            float v1 = bf2f(*(const short*)(A_lds + r*272 + 128 + lane*2));
            float pa = v0*a0 + v1*a1;
            #pragma unroll
            for (int off=32; off; off>>=1) pa += __shfl_xor(pa, off);
            if (lane==0 && node<NN) di[node] = pa;
        }
    }
    f32x4 Tacc[4], gh[4][3];
    {
        float tbv = tb[jb];
        #pragma unroll
        for (int m=0; m<4; ++m) Tacc[m] = (f32x4){tbv, tbv, tbv, tbv};
        #pragma unroll
        for (int g=0; g<3; ++g){
            float bv = bhh[g*128 + jb];
            #pragma unroll
            for (int m=0; m<4; ++m) gh[m][g] = (f32x4){bv, bv, bv, bv};
        }
    }
    #pragma unroll
    for (int ks=0; ks<4; ++ks){
        bf16x8 af[4];
        #pragma unroll
        for (int m=0; m<4; ++m)
            af[m] = *(const bf16x8*)(A_lds + (m*16+l15)*272 + ks*64 + (lhi<<4));
        bf16x8 tf = *(const bf16x8*)(twp + (size_t)((w*4 + ks)*64 + lane)*8);
        #pragma unroll
        for (int m=0; m<4; ++m)
            Tacc[m] = __builtin_amdgcn_mfma_f32_16x16x32_bf16(af[m], tf, Tacc[m], 0, 0, 0);
        #pragma unroll
        for (int g=0; g<3; ++g){
            bf16x8 wf = *(const bf16x8*)(whhp + (size_t)(((g*8+w)*4 + ks)*64 + lane)*8);
            #pragma unroll
            for (int m=0; m<4; ++m)
                gh[m][g] = __builtin_amdgcn_mfma_f32_16x16x32_bf16(af[m], wf, gh[m][g], 0, 0, 0);
        }
    }
    #pragma unroll
    for (int m=0; m<4; ++m){
        #pragma unroll
        for (int reg=0; reg<4; ++reg){
            int node = base + m*16 + lhi*4 + reg;
            if (node < NN){
                T16[(size_t)node*128 + jb]        = f2bf(Tacc[m][reg]);
                GH16[(size_t)node*384 + jb]       = f2bf(gh[m][0][reg]);
                GH16[(size_t)node*384 + 128 + jb] = f2bf(gh[m][1][reg]);
                GH16[(size_t)node*384 + 256 + jb] = f2bf(gh[m][2][reg]);
            }
        }
    }
}

// ================= layer 1 prep =================
__global__ __launch_bounds__(512) void k_l1_prep(
    const float* __restrict__ out0, const float* __restrict__ aw,
    const short* __restrict__ twp, const float* __restrict__ tb,
    const short* __restrict__ whhp, const float* __restrict__ bhh,
    short* __restrict__ x16, float* __restrict__ di, float* __restrict__ dj,
    short* __restrict__ T16, short* __restrict__ GH16)
{
    __shared__ __align__(16) char x_lds[64*272];
    const int t = threadIdx.x;
    const int base = blockIdx.x << 6;
    {
        int r = t >> 3, c0 = (t & 7) * 16;
        int node = base + r;
        int nc = node < NN ? node : NN-1;
        const float4* sp = (const float4*)(out0 + (size_t)nc*128 + c0);
        float4 f0 = sp[0], f1 = sp[1], f2 = sp[2], f3 = sp[3];
        union { short s[16]; int4 v[2]; } u;
        u.s[0]=f2bf(f0.x); u.s[1]=f2bf(f0.y); u.s[2]=f2bf(f0.z); u.s[3]=f2bf(f0.w);
        u.s[4]=f2bf(f1.x); u.s[5]=f2bf(f1.y); u.s[6]=f2bf(f1.z); u.s[7]=f2bf(f1.w);
        u.s[8]=f2bf(f2.x); u.s[9]=f2bf(f2.y); u.s[10]=f2bf(f2.z); u.s[11]=f2bf(f2.w);
        u.s[12]=f2bf(f3.x); u.s[13]=f2bf(f3.y); u.s[14]=f2bf(f3.z); u.s[15]=f2bf(f3.w);
        *(int4*)(x_lds + r*272 + c0*2)      = u.v[0];
        *(int4*)(x_lds + r*272 + c0*2 + 16) = u.v[1];
        if (node < NN){
            *(int4*)(x16 + (size_t)node*128 + c0)     = u.v[0];
            *(int4*)(x16 + (size_t)node*128 + c0 + 8) = u.v[1];
        }
    }
    __syncthreads();
    const int w = t >> 6, lane = t & 63;
    {
        float a0 = aw[lane], a1 = aw[64+lane], a2 = aw[128+lane], a3 = aw[192+lane];
        for (int i=0;i<8;++i){
            int r = w*8 + i;
            int node = base + r;
            float v0 = bf2f(*(const short*)(x_lds + r*272 + lane*2));
            float v1 = bf2f(*(const short*)(x_lds + r*272 + 128 + lane*2));
            float pa = v0*a0 + v1*a1;
            float pb = v0*a2 + v1*a3;
            #pragma unroll
            for (int off=32; off; off>>=1){ pa += __shfl_xor(pa,off); pb += __shfl_xor(pb,off); }
            if (lane==0 && node<NN){ di[node]=pa; dj[node]=pb; }
        }
    }
    const int l15 = lane & 15, lhi = lane >> 4;
    const int jb = w*16 + l15;
    f32x4 Tacc[4], gh[4][3];
    {
        float tbv = tb[jb];
        #pragma unroll
        for (int m=0; m<4; ++m) Tacc[m] = (f32x4){tbv, tbv, tbv, tbv};
        #pragma unroll
        for (int g=0; g<3; ++g){
            float bv = bhh[g*128 + jb];
            #pragma unroll
            for (int m=0; m<4; ++m) gh[m][g] = (f32x4){bv, bv, bv, bv};
        }
    }
    #pragma unroll
    for (int ks=0; ks<4; ++ks){
        bf16x8 af[4];
        #pragma unroll
        for (int m=0; m<4; ++m)
            af[m] = *(const bf16x8*)(x_lds + (m*16+l15)*272 + ks*64 + (lhi<<4));
        bf16x8 tf = *(const bf16x8*)(twp + (size_t)((w*4 + ks)*64 + lane)*8);
        #pragma unroll
        for (int m=0; m<4; ++m)
            Tacc[m] = __builtin_amdgcn_mfma_f32_16x16x32_bf16(af[m], tf, Tacc[m], 0, 0, 0);
        #pragma unroll
        for (int g=0; g<3; ++g){
            bf16x8 wf = *(const bf16x8*)(whhp + (size_t)(((g*8+w)*4 + ks)*64 + lane)*8);
            #pragma unroll
            for (int m=0; m<4; ++m)
                gh[m][g] = __builtin_amdgcn_mfma_f32_16x16x32_bf16(af[m], wf, gh[m][g], 0, 0, 0);
        }
    }
    #pragma unroll
    for (int m=0; m<4; ++m){
        #pragma unroll
        for (int reg=0; reg<4; ++reg){
            int node = base + m*16 + lhi*4 + reg;
            if (node < NN){
                T16[(size_t)node*128 + jb]        = f2bf(Tacc[m][reg]);
                GH16[(size_t)node*384 + jb]       = f2bf(gh[m][0][reg]);
                GH16[(size_t)node*384 + 128 + jb] = f2bf(gh[m][1][reg]);
                GH16[(size_t)node*384 + 256 + jb] = f2bf(gh[m][2][reg]);
            }
        }
    }
}

// ================= fused align+softmax, layer 0 =================
__global__ __launch_bounds__(256) void k_align0(
    const int* __restrict__ srcptr, const int* __restrict__ se2_id,
    const int* __restrict__ se2_dst, const int* __restrict__ inv_dst,
    const float* __restrict__ ea, const short* __restrict__ B16,
    const float* __restrict__ wn, const float* __restrict__ aw,
    const float* __restrict__ ab, const float* __restrict__ di,
    float* __restrict__ evu_tmp, float* __restrict__ avu)
{
    const int lane = threadIdx.x & 63;
    const int node = blockIdx.x*4 + (threadIdx.x >> 6);
    if (node >= NN) return;
    const int start = srcptr[node], end = srcptr[node+1];
    if (start >= end) return;
    float wn2a[10], wn2b[10];
    #pragma unroll
    for (int k=0;k<10;++k){
        wn2a[k] = wn[lane*49 + 39 + k];
        wn2b[k] = wn[(lane+64)*49 + 39 + k];
    }
    const float awa = aw[128+lane], awb = aw[192+lane];
    const float abv = ab[0];
    const float v1b = bf2f(B16[(size_t)node*128 + lane]);
    const float v2b = bf2f(B16[(size_t)node*128 + 64 + lane]);
    const int deg = end - start;
    if (deg <= 64){
        int myeid = 0; float mydi = 0.f; float ear[10];
        if (lane < deg){
            int pos = start + lane;
            myeid = se2_id[pos];
            mydi  = di[se2_dst[pos]];
            #pragma unroll
            for (int k=0;k<10;++k) ear[k] = ea[(size_t)myeid*10 + k];
        }
        float pv = NINF;
        for (int i=0;i<deg;++i){
            float v1 = v1b, v2 = v2b;
            #pragma unroll
            for (int k=0;k<10;++k){
                float e = __shfl(ear[k], i);
                v1 += e*wn2a[k]; v2 += e*wn2b[k];
            }
            v1 = lrelu(v1); v2 = lrelu(v2);
            float p = v1*awa + v2*awb;
            #pragma unroll
            for (int off=32; off; off>>=1) p += __shfl_xor(p, off);
            float pe = lrelu(p + __shfl(mydi, i) + abv);
            if (lane == i) pv = pe;
        }
        float cm = pv;
        #pragma unroll
        for (int off=32; off; off>>=1) cm = fmaxf(cm, __shfl_xor(cm, off));
        float ex = (lane < deg) ? __expf(pv - cm) : 0.f;
        float cs = ex;
        #pragma unroll
        for (int off=32; off; off>>=1) cs += __shfl_xor(cs, off);
        if (lane < deg) avu[inv_dst[myeid]] = ex / (cs + 1e-16f);
    } else {
        float mrun = NINF, srun = 0.f;
        for (int c0 = start; c0 < end; c0 += 64){
            int nE = min(64, end - c0);
            int myeid=0; float mydi=0.f; float ear[10];
            if (lane < nE){
                int pos = c0 + lane;
                myeid = se2_id[pos];
                mydi = di[se2_dst[pos]];
                #pragma unroll
                for (int k=0;k<10;++k) ear[k] = ea[(size_t)myeid*10 + k];
            }
            float pv = NINF;
            for (int i=0;i<nE;++i){
                float v1=v1b, v2=v2b;
                #pragma unroll
                for (int k=0;k<10;++k){
                    float e = __shfl(ear[k], i);
                    v1 += e*wn2a[k]; v2 += e*wn2b[k];
                }
                v1=lrelu(v1); v2=lrelu(v2);
                float p = v1*awa + v2*awb;
                #pragma unroll
                for (int off=32; off; off>>=1) p += __shfl_xor(p, off);
                float pe = lrelu(p + __shfl(mydi,i) + abv);
                if (lane == i) pv = pe;
            }
            if (lane < nE) evu_tmp[c0+lane] = pv;
            float cm = pv;
            #pragma unroll
            for (int off=32; off; off>>=1) cm = fmaxf(cm, __shfl_xor(cm,off));
            float nm = fmaxf(mrun, cm);
            float exs = (lane<nE)? __expf(pv-nm) : 0.f;
            float cs = exs;
            #pragma unroll
            for (int off=32; off; off>>=1) cs += __shfl_xor(cs, off);
            srun = srun*__expf(mrun-nm) + cs;
            mrun = nm;
        }
        float inv = 1.f/(srun + 1e-16f);
        for (int c0 = start; c0 < end; c0 += 64){
            int nE = min(64, end - c0);
            if (lane < nE){
                int pos = c0+lane;
                float pv = evu_tmp[pos];
                avu[inv_dst[se2_id[pos]]] = __expf(pv - mrun)*inv;
            }
        }
    }
}

// ================= fused align+softmax, layer 1 =================
__global__ __launch_bounds__(256) void k_align1(
    const int* __restrict__ srcptr, const int* __restrict__ se2_id,
    const int* __restrict__ se2_dst, const int* __restrict__ inv_dst,
    const float* __restrict__ di, const float* __restrict__ dj,
    const float* __restrict__ ab,
    float* __restrict__ evu_tmp, float* __restrict__ avu)
{
    const int lane = threadIdx.x & 63;
    const int node = blockIdx.x*4 + (threadIdx.x >> 6);
    if (node >= NN) return;
    const int start = srcptr[node], end = srcptr[node+1];
    if (start >= end) return;
    const float djs = dj[node] + ab[0];
    const int deg = end - start;
    if (deg <= 64){
        int myeid = 0; float pv = NINF;
        if (lane < deg){
            int pos = start + lane;
            myeid = se2_id[pos];
            pv = lrelu(di[se2_dst[pos]] + djs);
        }
        float cm = pv;
        #pragma unroll
        for (int off=32; off; off>>=1) cm = fmaxf(cm, __shfl_xor(cm, off));
        float ex = (lane < deg) ? __expf(pv - cm) : 0.f;
        float cs = ex;
        #pragma unroll
        for (int off=32; off; off>>=1) cs += __shfl_xor(cs, off);
        if (lane < deg) avu[inv_dst[myeid]] = ex / (cs + 1e-16f);
    } else {
        float mrun = NINF, srun = 0.f;
        for (int c0 = start; c0 < end; c0 += 64){
            int nE = min(64, end - c0);
            float pv = NINF;
            if (lane < nE){
                int pos = c0 + lane;
                pv = lrelu(di[se2_dst[pos]] + djs);
                evu_tmp[pos] = pv;
            }
            float cm = pv;
            #pragma unroll
            for (int off=32; off; off>>=1) cm = fmaxf(cm, __shfl_xor(cm,off));
            float nm = fmaxf(mrun, cm);
            float exs = (lane<nE)? __expf(pv-nm) : 0.f;
            float cs = exs;
            #pragma unroll
            for (int off=32; off; off>>=1) cs += __shfl_xor(cs, off);
            srun = srun*__expf(mrun-nm) + cs;
            mrun = nm;
        }
        float inv = 1.f/(srun + 1e-16f);
        for (int c0 = start; c0 < end; c0 += 64){
            int nE = min(64, end - c0);
            if (lane < nE){
                int pos = c0+lane;
                avu[inv_dst[se2_id[pos]]] = __expf(evu_tmp[pos] - mrun)*inv;
            }
        }
    }
}

// ================= heavy per-edge on dst-sorted edges (R5 structure) =================
__global__ __launch_bounds__(512) void k_edge_gru(
    const int* __restrict__ se_dst,
    const float* __restrict__ avu,
    const short* __restrict__ T16, const short* __restrict__ GH16,
    const short* __restrict__ HP16,
    const short* __restrict__ wihp, const float* __restrict__ bih,
    float* __restrict__ out)
{
    __shared__ __align__(16) char smem[64*132*4];   // c bf16 [64][272B] ; reused as h fp32 [64][132]
    __shared__ int dsts[64];
    __shared__ float av[64];
    char* const c_lds = smem;
    const int t = threadIdx.x;
    const int p0 = blockIdx.x << 6;
    if (t < 64){
        dsts[t] = se_dst[p0 + t];
        av[t] = avu[p0 + t];
    }
    __syncthreads();
    // ---- c = elu(av * T16[dst]) -> c_lds bf16 ----
    #pragma unroll
    for (int it=0; it<2; ++it){
        int cid = it*512 + t;
        int row = cid >> 4, ch = cid & 15;
        int d = dsts[row];
        float a = av[row];
        bf16x8 tv = *(const bf16x8*)(T16 + (size_t)d*128 + ch*8);
        float c0 = elu1(a*bf2f(tv[0])), c1 = elu1(a*bf2f(tv[1]));
        float c2 = elu1(a*bf2f(tv[2])), c3 = elu1(a*bf2f(tv[3]));
        float c4 = elu1(a*bf2f(tv[4])), c5 = elu1(a*bf2f(tv[5]));
        float c6 = elu1(a*bf2f(tv[6])), c7 = elu1(a*bf2f(tv[7]));
        int4 pk;
        pk.x = (int)cvtpk_bf16(c0, c1);
        pk.y = (int)cvtpk_bf16(c2, c3);
        pk.z = (int)cvtpk_bf16(c4, c5);
        pk.w = (int)cvtpk_bf16(c6, c7);
        *(int4*)(c_lds + row*272 + ch*16) = pk;
    }
    __syncthreads();
    const int w = t >> 6, lane = t & 63;
    const int l15 = lane & 15, lhi = lane >> 4;
    const int jb = w*16 + l15;
    // ---- gi GEMM ----
    f32x4 gi[4][3];
    #pragma unroll
    for (int g=0; g<3; ++g){
        float bv = bih[g*128 + jb];
        #pragma unroll
        for (int m=0; m<4; ++m) gi[m][g] = (f32x4){bv, bv, bv, bv};
    }
    #pragma unroll
    for (int ks=0; ks<4; ++ks){
        bf16x8 cf[4];
        #pragma unroll
        for (int m=0; m<4; ++m)
            cf[m] = *(const bf16x8*)(c_lds + (m*16+l15)*272 + ks*64 + (lhi<<4));
        #pragma unroll
        for (int g=0; g<3; ++g){
            bf16x8 wf = *(const bf16x8*)(wihp + (size_t)(((g*8+w)*4 + ks)*64 + lane)*8);
            #pragma unroll
            for (int m=0; m<4; ++m)
                gi[m][g] = __builtin_amdgcn_mfma_f32_16x16x32_bf16(cf[m], wf, gi[m][g], 0, 0, 0);
        }
    }
    // ---- GRU epilogue: independent gathers (ILP) ----
    float hreg[4][4];
    #pragma unroll
    for (int m=0; m<4; ++m){
        #pragma unroll
        for (int reg=0; reg<4; ++reg){
            int e = m*16 + lhi*4 + reg;
            int d = dsts[e];
            const short* gh = GH16 + (size_t)d*384;
            float r = sigm(gi[m][0][reg] + bf2f(gh[jb]));
            float z = sigm(gi[m][1][reg] + bf2f(gh[128+jb]));
            float n = tanh_fast(gi[m][2][reg] + r*bf2f(gh[256+jb]));
            float hp = bf2f(HP16[(size_t)d*128 + jb]);
            hreg[m][reg] = (1.f - z)*n + z*hp;
        }
    }
    __syncthreads();   // c reads done; smem becomes h[64][132] fp32
    {
        float* hlds = (float*)smem;
        #pragma unroll
        for (int m=0; m<4; ++m){
            #pragma unroll
            for (int reg=0; reg<4; ++reg){
                int e = m*16 + lhi*4 + reg;
                hlds[e*132 + jb] = hreg[m][reg];
            }
        }
    }
    __syncthreads();
    // ---- run-compressed scatter-add over 16-edge windows ----
    {
        const int j = t & 127, eg = t >> 7;
        const float* hlds = (const float*)smem;
        float acc = 0.f; int prev = -1;
        #pragma unroll
        for (int el=0; el<16; ++el){
            int e = eg*16 + el;
            int d = dsts[e];
            float v = hlds[e*132 + j];
            if (d == prev) acc += v;
            else {
                if (prev >= 0) atomicAdd(out + (size_t)prev*128 + j, acc);
                acc = v; prev = d;
            }
        }
        atomicAdd(out + (size_t)prev*128 + j, acc);
    }
}

extern "C" void kernel_launch(void* const* d_in, const int* in_sizes, int n_in,
                              void* d_out, int out_size, void* d_ws, size_t ws_size,
                              hipStream_t stream) {
    const float* x    = (const float*)d_in[0];
    const int*   eidx = (const int*)d_in[1];
    const int*   esrc = eidx;
    const int*   edst = eidx + NE;
    const float* ea   = (const float*)d_in[2];
    const float* a_w  = (const float*)d_in[3];
    const float* a_b  = (const float*)d_in[4];
    const float* n_w  = (const float*)d_in[5];
    const float* n_b  = (const float*)d_in[6];
    const float* al_w0= (const float*)d_in[7];
    const float* al_b0= (const float*)d_in[8];
    const float* t_w0 = (const float*)d_in[9];
    const float* t_b0 = (const float*)d_in[10];
    const float* wih0 = (const float*)d_in[11];
    const float* whh0 = (const float*)d_in[12];
    const float* bih0 = (const float*)d_in[13];
    const float* bhh0 = (const float*)d_in[14];
    const float* al_w1= (const float*)d_in[15];
    const float* al_b1= (const float*)d_in[16];
    const float* t_w1 = (const float*)d_in[17];
    const float* t_b1 = (const float*)d_in[18];
    const float* wih1 = (const float*)d_in[19];
    const float* whh1 = (const float*)d_in[20];
    const float* bih1 = (const float*)d_in[21];
    const float* bhh1 = (const float*)d_in[22];

    float* ws   = (float*)d_ws;
    float* out0 = ws;                               // NN*128 f (zeroed in k_big)
    float* avu  = out0 + (size_t)NN*128;            // NE
    float* evu_tmp = avu + NE;                      // NE
    float* di   = evu_tmp + NE;                     // NN
    float* dj   = di + NN;                          // NN
    unsigned* hist_d = (unsigned*)(dj + NN);        // NN
    unsigned* hist_s = hist_d + NN;                 // NN
    int* srcptr = (int*)(hist_s + NN);              // NN+1 (cursor_src doubles as srcptr base? no - separate)
    unsigned* cur_d  = (unsigned*)(srcptr + NN + 1);// NN
    unsigned* cur_s  = cur_d + NN;                  // NN
    int* se_dst  = (int*)(cur_s + NN);              // NE
    int* inv_dst = se_dst + NE;                     // NE
    int* se2_id  = inv_dst + NE;                    // NE
    int* se2_dst = se2_id + NE;                     // NE
    short* A16  = (short*)(se2_dst + NE);           // NN*128
    short* BX16 = A16 + (size_t)NN*128;             // B16 (l0) then x16 (l1)
    short* T16  = BX16 + (size_t)NN*128;            // NN*128
    short* GH16 = T16 + (size_t)NN*128;             // NN*384
    short* wp0  = GH16 + (size_t)NN*384;            // 49152 each
    short* wp1  = wp0 + 49152;
    short* wh0p = wp1 + 49152;
    short* wh1p = wh0p + 49152;
    short* tp0  = wh1p + 49152;                     // 16384 each
    short* tp1  = tp0 + 16384;
    short* wap  = tp1 + 16384;                      // 8192 each (K64 packs)
    short* wnp  = wap + 8192;

    // single memset: histograms only (out0/d_out zeroed inside k_big)
    hipMemsetAsync(hist_d, 0, (size_t)2*NN*sizeof(unsigned), stream);

    // node 2: pack + histogram
    k_setup<<<dim3(960 + (NE+255)/256), dim3(256), 0, stream>>>(
        wih0, wih1, whh0, whh1, t_w0, t_w1, a_w, n_w,
        wp0, wp1, wh0p, wh1p, tp0, tp1, wap, wnp,
        esrc, edst, hist_d, hist_s);
    // node 3: dual scan
    k_scan2<<<dim3(2), dim3(1024), 0, stream>>>(hist_d, cur_d, hist_s, cur_s, srcptr);
    // node 4: l0_prep + scatter + zero(out0,d_out)
    k_big<<<dim3(391 + (NE+511)/512), dim3(512), 0, stream>>>(
        x, a_b, n_b, al_w0, wap, wnp, tp0, t_b0, wh0p, bhh0,
        A16, BX16, di, T16, GH16,
        esrc, edst, cur_d, cur_s, se_dst, inv_dst, se2_id, se2_dst,
        out0, (float*)d_out);
    // node 5: align+softmax L0
    k_align0<<<dim3((NN+3)/4), dim3(256), 0, stream>>>(srcptr, se2_id, se2_dst, inv_dst,
                                                 ea, BX16, n_w, al_w0, al_b0, di, evu_tmp, avu);
    // node 6: edge GRU L0
    k_edge_gru<<<dim3(NE/64), dim3(512), 0, stream>>>(se_dst, avu, T16, GH16, A16,
                                                      wp0, bih0, out0);
    // node 7: l1 prep
    k_l1_prep<<<dim3((NN+63)/64), dim3(512), 0, stream>>>(out0, al_w1, tp1, t_b1, wh1p, bhh1,
                                                          BX16, di, dj, T16, GH16);
    // node 8: align+softmax L1
    k_align1<<<dim3((NN+3)/4), dim3(256), 0, stream>>>(srcptr, se2_id, se2_dst, inv_dst,
                                                 di, dj, al_b1, evu_tmp, avu);
    // node 9: edge GRU L1
    k_edge_gru<<<dim3(NE/64), dim3(512), 0, stream>>>(se_dst, avu, T16, GH16, BX16,
                                                      wp1, bih1, (float*)d_out);
}